// Round 8
// baseline (455.982 us; speedup 1.0000x reference)
//
#include <hip/hip_runtime.h>
#include <hip/hip_bf16.h>

#define NB 4096
#define PLEN 14
#define NROWS (NB*PLEN)   // 57344
#define BN_EPS 1e-5f

typedef __bf16 bf16x8 __attribute__((ext_vector_type(8)));
typedef float  f32x4  __attribute__((ext_vector_type(4)));

// NOTE (R4-R7 post-mortem): single-kernel + software grid barrier produced
// deterministic wrong results (identical error across two different coherent
// read mechanisms) — root cause never identified. This file uses dispatch
// boundaries for all cross-block dataflow (stats, weights), the structure
// proven correct in R1-R3. Block-local tensors (pre*, omax/omin) never cross
// blocks: block b always owns rows [b*112, b*112+112) / chains [b*8, b*8+8).

// ---- pre-kernel: zero stats, transpose weights to [n][k] bf16 -------------
__global__ __launch_bounds__(256) void wprep_kernel(
    const float* __restrict__ W2, const float* __restrict__ W3,
    const float* __restrict__ W4, const float* __restrict__ W5,
    __bf16* __restrict__ wt2, __bf16* __restrict__ wt3,
    __bf16* __restrict__ wt4, __bf16* __restrict__ wt5,
    float* __restrict__ stats)
{
    int idx = blockIdx.x*256 + threadIdx.x;
    if (idx < 20480) { stats[idx] = 0.f; return; }
    idx -= 20480;
    if (idx < 4096) { int n=idx>>6, k=idx&63; wt2[idx]=(__bf16)W2[k*64+n]; return; }
    idx -= 4096;
    if (idx < 4096) { int n=idx>>6, k=idx&63; wt3[idx]=(__bf16)W3[k*64+n]; return; }
    idx -= 4096;
    if (idx < 8192) { int n=idx>>6, k=idx&63; wt4[idx]=(__bf16)W4[k*128+n]; return; }
    idx -= 8192;
    int n = idx >> 7, k = idx & 127;
    wt5[idx] = (__bf16)W5[k*1024 + n];    // [1024][128]
}

// ---- Layer 1: fp32 vector (din=3), agg(x) @ W1 + b1, stats ----------------
__global__ __launch_bounds__(256) void l1_kernel(
    const float* __restrict__ x,     // [NB][3][PLEN]
    const float* __restrict__ W,     // [3][64]
    const float* __restrict__ bias,  // [64]
    float* __restrict__ pre,         // [NROWS][64]
    float* __restrict__ stats)       // set 0
{
    const int col  = threadIdx.x & 63;
    const int sub  = threadIdx.x >> 6;
    const int chain = blockIdx.x * 4 + sub;
    const float w0 = W[col], w1 = W[64+col], w2 = W[128+col];
    const float bb = bias[col];
    const float* xb = x + chain*3*PLEN;
    float s = 0.f, s2 = 0.f;
    #pragma unroll
    for (int p = 0; p < PLEN; p++) {
        float u0 = 0.f, u1 = 0.f, u2 = 0.f;
        if (p > 0)      { u0 += xb[p-1]; u1 += xb[PLEN+p-1]; u2 += xb[2*PLEN+p-1]; }
        if (p < PLEN-1) { u0 += xb[p+1]; u1 += xb[PLEN+p+1]; u2 += xb[2*PLEN+p+1]; }
        float v = u0*w0 + u1*w1 + u2*w2 + bb;
        pre[(chain*PLEN + p)*64 + col] = v;
        s += v; s2 += v*v;
    }
    __shared__ float ss[4][64], ssq[4][64];
    ss[sub][col] = s; ssq[sub][col] = s2;
    __syncthreads();
    if (sub == 0) {
        float ts  = ss[0][col]+ss[1][col]+ss[2][col]+ss[3][col];
        float ts2 = ssq[0][col]+ssq[1][col]+ssq[2][col]+ssq[3][col];
        atomicAdd(&stats[col], ts);
        atomicAdd(&stats[1024+col], ts2);
    }
}

// ---- fused layer (L2-L4): BN+ReLU+chain_agg -> MFMA (B from global) -------
template<int NOUT>
__global__ __launch_bounds__(256) void layer_kernel(
    const float* __restrict__ prev,      // [NROWS][64]
    const float* __restrict__ st_in,     // stats of prev (sums)
    const float* __restrict__ gamma, const float* __restrict__ beta,
    const __bf16* __restrict__ wt,       // [NOUT][64] transposed bf16
    const float* __restrict__ bias,
    float* __restrict__ outp,            // [NROWS][NOUT]
    float* __restrict__ st_out)
{
    constexpr int KP = 72;
    __shared__ __align__(16) short sA[112*KP];   // 16128 B
    const int tid = threadIdx.x, wave = tid >> 6, lane = tid & 63;
    const int rowbase = blockIdx.x * 112;

    {   // A = chain_agg(relu(bn(prev))): thread owns 1 chain x 2 cols
        const int ch = tid >> 5, c2 = (tid & 31)*2;
        float mu0 = st_in[c2]*(1.f/NROWS);
        float v0  = st_in[1024+c2]*(1.f/NROWS) - mu0*mu0;
        float a0  = gamma[c2]*rsqrtf(v0+BN_EPS), c0 = beta[c2]-mu0*a0;
        float mu1 = st_in[c2+1]*(1.f/NROWS);
        float v1  = st_in[1024+c2+1]*(1.f/NROWS) - mu1*mu1;
        float a1  = gamma[c2+1]*rsqrtf(v1+BN_EPS), c1 = beta[c2+1]-mu1*a1;
        float h0[14], h1[14];
        const float* src = prev + (size_t)(rowbase + ch*14)*64 + c2;
        #pragma unroll
        for (int r = 0; r < 14; ++r) {
            float2 v = *reinterpret_cast<const float2*>(src + r*64);
            h0[r] = fmaxf(a0*v.x + c0, 0.f);
            h1[r] = fmaxf(a1*v.y + c1, 0.f);
        }
        #pragma unroll
        for (int r = 0; r < 14; ++r) {
            float g0 = (r>0 ? h0[r-1] : 0.f) + (r<13 ? h0[r+1] : 0.f);
            float g1 = (r>0 ? h1[r-1] : 0.f) + (r<13 ? h1[r+1] : 0.f);
            union { __bf16 b[2]; unsigned u; } pk;
            pk.b[0] = (__bf16)g0; pk.b[1] = (__bf16)g1;
            *reinterpret_cast<unsigned*>(&sA[(ch*14+r)*KP + c2]) = pk.u;
        }
    }

    const int m = lane & 15, q = lane >> 4;
    constexpr int NCH = NOUT/64;
    // B fragments straight from global (weights L2-resident)
    bf16x8 bfrag[NCH][2];
    #pragma unroll
    for (int cc = 0; cc < NCH; ++cc)
        #pragma unroll
        for (int s = 0; s < 2; ++s)
            bfrag[cc][s] = *reinterpret_cast<const bf16x8*>(
                wt + (cc*64 + wave*16 + m)*64 + s*32 + q*8);

    __syncthreads();

    f32x4 acc[NCH][7];
    #pragma unroll
    for (int cc = 0; cc < NCH; ++cc)
        #pragma unroll
        for (int t = 0; t < 7; ++t) acc[cc][t] = (f32x4){0.f,0.f,0.f,0.f};

    #pragma unroll
    for (int s = 0; s < 2; ++s) {
        bf16x8 af[7];
        #pragma unroll
        for (int t = 0; t < 7; ++t)
            af[t] = *reinterpret_cast<const bf16x8*>(&sA[(t*16+m)*KP + s*32 + q*8]);
        #pragma unroll
        for (int cc = 0; cc < NCH; ++cc)
            #pragma unroll
            for (int t = 0; t < 7; ++t)
                acc[cc][t] = __builtin_amdgcn_mfma_f32_16x16x32_bf16(af[t], bfrag[cc][s], acc[cc][t], 0, 0, 0);
    }

    #pragma unroll
    for (int cc = 0; cc < NCH; ++cc) {
        const int ocol = cc*64 + wave*16 + m;
        const float bb = bias[ocol];
        float s = 0.f, s2 = 0.f;
        #pragma unroll
        for (int t = 0; t < 7; ++t)
            #pragma unroll
            for (int r = 0; r < 4; ++r) {
                float v = acc[cc][t][r] + bb;
                outp[(size_t)(rowbase + t*16 + q*4 + r)*NOUT + ocol] = v;
                s += v; s2 += v*v;
            }
        s  += __shfl_xor(s, 16);  s  += __shfl_xor(s, 32);
        s2 += __shfl_xor(s2, 16); s2 += __shfl_xor(s2, 32);
        if (lane < 16) {
            atomicAdd(&st_out[ocol], s);
            atomicAdd(&st_out[1024 + ocol], s2);
        }
    }
}

// ---- Layer 5: BN+ReLU+agg, reg-A, B from global, barrier-free K-loop ------
__global__ __launch_bounds__(256, 2) void l5_kernel(
    const float* __restrict__ prev,      // [NROWS][128] (pre4)
    const float* __restrict__ st_in,
    const float* __restrict__ gamma, const float* __restrict__ beta,
    const __bf16* __restrict__ wt5,      // [1024][128] transposed bf16
    const float* __restrict__ bias,
    float* __restrict__ omax,            // [NB][1024]
    float* __restrict__ omin,            // [NB][1024]
    float* __restrict__ st_out)
{
    __shared__ __align__(16) char lds[32256];
    short* sA = (short*)lds;                     // staging: 112*136*2 = 30464 B
    const int tid = threadIdx.x, wave = tid >> 6, lane = tid & 63;
    const int m = lane & 15, q = lane >> 4;
    const int rowbase = blockIdx.x * 112;

    {   // A = chain_agg(relu(bn(pre4))): thread owns 1 chain x 4 cols
        const int ch = tid >> 5, c4 = (tid & 31)*4;
        float aa[4], cc4[4];
        #pragma unroll
        for (int j = 0; j < 4; ++j) {
            float mu = st_in[c4+j]*(1.f/NROWS);
            float vr = st_in[1024+c4+j]*(1.f/NROWS) - mu*mu;
            aa[j] = gamma[c4+j]*rsqrtf(vr+BN_EPS);
            cc4[j] = beta[c4+j] - mu*aa[j];
        }
        float h[14][4];
        const float* src = prev + (size_t)(rowbase + ch*14)*128 + c4;
        #pragma unroll
        for (int r = 0; r < 14; ++r) {
            float4 v = *reinterpret_cast<const float4*>(src + r*128);
            h[r][0] = fmaxf(aa[0]*v.x + cc4[0], 0.f);
            h[r][1] = fmaxf(aa[1]*v.y + cc4[1], 0.f);
            h[r][2] = fmaxf(aa[2]*v.z + cc4[2], 0.f);
            h[r][3] = fmaxf(aa[3]*v.w + cc4[3], 0.f);
        }
        #pragma unroll
        for (int r = 0; r < 14; ++r) {
            union { __bf16 b[4]; uint2 u; } pk;
            #pragma unroll
            for (int j = 0; j < 4; ++j) {
                float g = (r>0 ? h[r-1][j] : 0.f) + (r<13 ? h[r+1][j] : 0.f);
                pk.b[j] = (__bf16)g;
            }
            *reinterpret_cast<uint2*>(&sA[(ch*14+r)*136 + c4]) = pk.u;
        }
    }
    __syncthreads();

    bf16x8 af[7][4];                             // 112 VGPR of A fragments
    #pragma unroll
    for (int t = 0; t < 7; ++t)
        #pragma unroll
        for (int kk = 0; kk < 4; ++kk)
            af[t][kk] = *reinterpret_cast<const bf16x8*>(&sA[(t*16 + m)*136 + kk*32 + q*8]);
    __syncthreads();   // A reads done; LDS becomes per-wave epilogue slabs

    float* slab = reinterpret_cast<float*>(lds) + wave*2016;  // [112][18] per wave

    #pragma unroll 1
    for (int c = 0; c < 16; ++c) {
        bf16x8 bf[4];
        #pragma unroll
        for (int k4 = 0; k4 < 4; ++k4)
            bf[k4] = *reinterpret_cast<const bf16x8*>(
                wt5 + (size_t)(c*64 + wave*16 + m)*128 + k4*32 + q*8);
        f32x4 acc[7];
        #pragma unroll
        for (int t = 0; t < 7; ++t) acc[t] = (f32x4){0.f,0.f,0.f,0.f};
        #pragma unroll
        for (int k4 = 0; k4 < 4; ++k4)
            #pragma unroll
            for (int t = 0; t < 7; ++t)
                acc[t] = __builtin_amdgcn_mfma_f32_16x16x32_bf16(af[t][k4], bf[k4], acc[t], 0, 0, 0);

        const int ocol = c*64 + wave*16 + m;
        const float bb = bias[ocol];
        const int r0 = q*4;
        float s = 0.f, s2 = 0.f;
        #pragma unroll
        for (int t = 0; t < 7; ++t)
            #pragma unroll
            for (int r = 0; r < 4; ++r) {
                float v = acc[t][r] + bb;
                s += v; s2 += v*v;
                slab[(t*16 + r0 + r)*18 + m] = v;
            }
        s  += __shfl_xor(s, 16);  s  += __shfl_xor(s, 32);
        s2 += __shfl_xor(s2, 16); s2 += __shfl_xor(s2, 32);
        if (lane < 16) {
            atomicAdd(&st_out[ocol], s);
            atomicAdd(&st_out[1024 + ocol], s2);
        }
        // chain min/max from the wave-private slab (same-wave DS is ordered)
        #pragma unroll
        for (int pi = 0; pi < 2; ++pi) {
            int ch  = (lane + 64*pi) >> 4;
            int col = lane & 15;
            float mx = -3.4e38f, mn = 3.4e38f;
            #pragma unroll
            for (int pp = 0; pp < PLEN; ++pp) {
                float v = slab[(ch*PLEN + pp)*18 + col];
                mx = fmaxf(mx, v); mn = fminf(mn, v);
            }
            size_t off = (size_t)(blockIdx.x*8 + ch)*1024 + c*64 + wave*16 + col;
            omax[off] = mx; omin[off] = mn;
        }
    }
}

// ---- head+cluster fused: one block per batch row --------------------------
__global__ __launch_bounds__(256) void headclu_kernel(
    const float* __restrict__ omax, const float* __restrict__ omin,
    const float* __restrict__ stats,
    const float* __restrict__ gamma, const float* __restrict__ beta,
    const float* __restrict__ embW, const float* __restrict__ embB,
    const float* __restrict__ cluW,
    float* __restrict__ e,            // [NB][10]
    float* __restrict__ cOut,         // [NB][800]
    float* __restrict__ dOut,         // or null
    const float* __restrict__ eOther, // e1 or null
    float* __restrict__ simOut)       // or null
{
    const int b = blockIdx.x, tid = threadIdx.x;
    const int wave = tid >> 6, lane = tid & 63;
    float acc[10];
    #pragma unroll
    for (int j = 0; j < 10; ++j) acc[j] = 0.f;
    #pragma unroll
    for (int i = 0; i < 4; ++i) {
        int k = tid + i*256;
        float mu  = stats[k]*(1.f/NROWS);
        float var = stats[1024+k]*(1.f/NROWS) - mu*mu;
        float a = gamma[k]*rsqrtf(var+BN_EPS);
        float c = beta[k] - mu*a;
        float v = (a >= 0.f) ? omax[(size_t)b*1024 + k] : omin[(size_t)b*1024 + k];
        float h = fmaxf(a*v + c, 0.f);
        #pragma unroll
        for (int j = 0; j < 10; ++j) acc[j] += h * embW[k*10 + j];
    }
    #pragma unroll
    for (int j = 0; j < 10; ++j) {
        acc[j] += __shfl_down(acc[j], 32);
        acc[j] += __shfl_down(acc[j], 16);
        acc[j] += __shfl_down(acc[j], 8);
        acc[j] += __shfl_down(acc[j], 4);
        acc[j] += __shfl_down(acc[j], 2);
        acc[j] += __shfl_down(acc[j], 1);
    }
    __shared__ float red[4][10];
    __shared__ float se[10];
    if (lane == 0)
        #pragma unroll
        for (int j = 0; j < 10; ++j) red[wave][j] = acc[j];
    __syncthreads();
    if (tid < 10) {
        float t = red[0][tid]+red[1][tid]+red[2][tid]+red[3][tid] + embB[tid];
        se[tid] = t;
        e[b*10 + tid] = t;
    }
    __syncthreads();

    float ev[10];
    #pragma unroll
    for (int j = 0; j < 10; ++j) ev[j] = se[j];
    float dloc[4], qloc[4], qs = 0.f;
    #pragma unroll
    for (int i = 0; i < 4; ++i) {
        int mm = tid + i*256;
        float dd = 0.f;
        if (mm < 800) {
            #pragma unroll
            for (int j = 0; j < 10; ++j) { float t = ev[j] - cluW[mm*10 + j]; dd += t*t; }
        }
        dloc[i] = dd;
        float qv = (mm < 800) ? 1.f/(1.f + dd) : 0.f;
        qloc[i] = qv; qs += qv;
    }
    float t = qs;
    t += __shfl_down(t,32); t += __shfl_down(t,16); t += __shfl_down(t,8);
    t += __shfl_down(t,4);  t += __shfl_down(t,2);  t += __shfl_down(t,1);
    __shared__ float sred[4];
    if (lane == 0) sred[wave] = t;
    __syncthreads();
    float inv = 1.f / (sred[0]+sred[1]+sred[2]+sred[3]);
    #pragma unroll
    for (int i = 0; i < 4; ++i) {
        int mm = tid + i*256;
        if (mm < 800) {
            cOut[(size_t)b*800 + mm] = qloc[i]*inv;
            if (dOut) dOut[(size_t)b*800 + mm] = dloc[i];
        }
    }
    if (simOut && tid == 0) {
        float ss = 0.f;
        #pragma unroll
        for (int j = 0; j < 10; ++j) {
            float df = eOther[b*10 + j] - se[j] + 1e-6f;   // e1 - e2 + eps
            ss += df*df;
        }
        simOut[b] = sqrtf(ss);
    }
}

// ---------------------------------------------------------------------------
extern "C" void kernel_launch(void* const* d_in, const int* in_sizes, int n_in,
                              void* d_out, int out_size, void* d_ws, size_t ws_size,
                              hipStream_t stream)
{
    const float* x[2] = {(const float*)d_in[0], (const float*)d_in[1]};
    const float *W[5], *bi[5], *ga[5], *be[5];
    for (int l = 0; l < 5; l++) {
        W[l]  = (const float*)d_in[2 + 4*l];
        bi[l] = (const float*)d_in[3 + 4*l];
        ga[l] = (const float*)d_in[4 + 4*l];
        be[l] = (const float*)d_in[5 + 4*l];
    }
    const float* embW = (const float*)d_in[22];
    const float* embB = (const float*)d_in[23];
    const float* cluW = (const float*)d_in[24];
    float* out = (float*)d_out;
    float* ws  = (float*)d_ws;

    // workspace (floats), ~78 MB total — layout proven in R1-R3
    float*  preA  = ws;                          // NROWS*64
    float*  preB  = ws + 3670016;                // NROWS*128
    float*  omax  = ws + 11010048;               // NB*1024
    float*  omin  = ws + 15204352;               // NB*1024
    float*  stats = ws + 19398656;               // 20480
    __bf16* wt2   = (__bf16*)(ws + 19419136);    // [64][64]
    __bf16* wt3   = wt2 + 4096;                  // [64][64]
    __bf16* wt4   = wt2 + 8192;                  // [128][64]
    __bf16* wt5   = wt2 + 16384;                 // [1024][128]

    wprep_kernel<<<656, 256, 0, stream>>>(W[1], W[2], W[3], W[4],
                                          wt2, wt3, wt4, wt5, stats);

    float* simO = out;
    float* c1O  = out + 4096;
    float* c2O  = out + 3280896;
    float* e1O  = out + 6557696;
    float* e2O  = out + 6598656;
    float* d1O  = out + 6639616;

    for (int inp = 0; inp < 2; inp++) {
        float* st = stats + inp*10240;
        l1_kernel<<<NB/4, 256, 0, stream>>>(x[inp], W[0], bi[0], preA, st);
        layer_kernel<64><<<NROWS/112, 256, 0, stream>>>(
            preA, st, ga[0], be[0], wt2, bi[1], preB, st + 2048);
        layer_kernel<64><<<NROWS/112, 256, 0, stream>>>(
            preB, st + 2048, ga[1], be[1], wt3, bi[2], preA, st + 4096);
        layer_kernel<128><<<NROWS/112, 256, 0, stream>>>(
            preA, st + 4096, ga[2], be[2], wt4, bi[3], preB, st + 6144);
        l5_kernel<<<NROWS/112, 256, 0, stream>>>(
            preB, st + 6144, ga[3], be[3], wt5, bi[4], omax, omin, st + 8192);
        headclu_kernel<<<NB, 256, 0, stream>>>(
            omax, omin, st + 8192, ga[4], be[4], embW, embB, cluW,
            (inp == 0) ? e1O : e2O,
            (inp == 0) ? c1O : c2O,
            (inp == 0) ? d1O : nullptr,
            (inp == 0) ? nullptr : e1O,
            (inp == 0) ? nullptr : simO);
    }
}